// Round 12
// baseline (602.167 us; speedup 1.0000x reference)
//
#include <hip/hip_runtime.h>
#include <math.h>

typedef unsigned short u16;
typedef __attribute__((ext_vector_type(4))) float f32x4;
typedef __attribute__((ext_vector_type(8))) short bf16x8;

#define GLOBAL_AS __attribute__((address_space(1)))
#define LDS_AS __attribute__((address_space(3)))

__device__ __forceinline__ u16 f2bf(float f) {
  unsigned u = __builtin_bit_cast(unsigned, f);
  unsigned lsb = (u >> 16) & 1u;
  u += 0x7fffu + lsb;            // round-to-nearest-even
  return (u16)(u >> 16);
}

__device__ __forceinline__ float bf2f(u16 b) {
  return __builtin_bit_cast(float, ((unsigned)b) << 16);
}

__device__ __forceinline__ void gload16(const void* g, void* l) {
  __builtin_amdgcn_global_load_lds((const GLOBAL_AS void*)g, (LDS_AS void*)l, 16, 0, 0);
}

// ---- fused prologue: mean_v, mean_t, cast fc_w, pad-cast w1,w2, pad b1 ------
__global__ __launch_bounds__(256) void prologue_kernel(
    const float* __restrict__ vision, const float* __restrict__ text,
    const float* __restrict__ fc_w, const float* __restrict__ w1,
    const float* __restrict__ w2, const float* __restrict__ b1,
    u16* __restrict__ mean_v, u16* __restrict__ mean_t,
    u16* __restrict__ fcw_bf, u16* __restrict__ w1p, u16* __restrict__ w2p,
    float* __restrict__ b1p)
{
  const int n_mv = 4096 * 192;   // N * D/4
  const int n_mt = 4096 * 128;   // M * Din/4
  const int n_fcw = 768 * 512;
  const int n_w1 = 256 * 768;
  const int n_w2 = 768 * 256;
  int id = blockIdx.x * 256 + threadIdx.x;

  if (id < n_mv) {               // mean over Lv=16 of vision[N][16][768]
    int n = id / 192, c = id % 192;
    const f32x4* x = (const f32x4*)vision + (size_t)n * 16 * 192 + c;
    f32x4 s = {0.f, 0.f, 0.f, 0.f};
#pragma unroll
    for (int l = 0; l < 16; ++l) s += __builtin_nontemporal_load(&x[(size_t)l * 192]);
    s *= (1.f / 16.f);
    ushort4 o; o.x = f2bf(s.x); o.y = f2bf(s.y); o.z = f2bf(s.z); o.w = f2bf(s.w);
    ((ushort4*)mean_v)[id] = o;
    return;
  }
  id -= n_mv;
  if (id < n_mt) {               // mean over Lt=77 of text[M][77][512]
    int n = id / 128, c = id % 128;
    const f32x4* x = (const f32x4*)text + (size_t)n * 77 * 128 + c;
    f32x4 s = {0.f, 0.f, 0.f, 0.f};
#pragma unroll 11
    for (int l = 0; l < 77; ++l) s += __builtin_nontemporal_load(&x[(size_t)l * 128]);
    s *= (1.f / 77.f);
    ushort4 o; o.x = f2bf(s.x); o.y = f2bf(s.y); o.z = f2bf(s.z); o.w = f2bf(s.w);
    ((ushort4*)mean_t)[id] = o;
    return;
  }
  id -= n_mt;
  if (id < n_fcw) { fcw_bf[id] = f2bf(fc_w[id]); return; }
  id -= n_fcw;
  if (id < n_w1) {
    int r = id / 768;
    w1p[id] = (r < 192) ? f2bf(w1[id]) : (u16)0;
    return;
  }
  id -= n_w1;
  if (id < n_w2) {
    int r = id / 256, c = id % 256;
    w2p[id] = (c < 192) ? f2bf(w2[(size_t)r * 192 + c]) : (u16)0;
    return;
  }
  id -= n_w2;
  if (id < 256) b1p[id] = (id < 192) ? b1[id] : 0.f;
}

// ------- 256x256 deep-pipelined NT bf16 GEMM, C bf16 = exp(alpha * A@B^T) ---
// BK=32, 3 LDS buffers, stage-2-ahead, counted vmcnt, 1 raw barrier per iter.
// XCD-swizzled blockIdx. C written via LDS-staged 256x128 stripes. Row
// exp-sums -> dsum[row][gridx] fp32 partials (deterministic, no atomics).
__global__ __launch_bounds__(512, 2) void gemm256_exp_bf16(
    const u16* __restrict__ A, const u16* __restrict__ B, float alpha,
    u16* __restrict__ C, float* __restrict__ dsum, int N, int K, int lda, int ldb)
{
  __shared__ char lds[98304];          // A bufs 0..48K, B bufs 48K..96K
  const int tid = threadIdx.x;
  const int w = tid >> 6, lane = tid & 63;

  // XCD-aware bijective swizzle
  const int gx = gridDim.x;
  const int nb = gx * gridDim.y;
  int b0 = blockIdx.y * gx + blockIdx.x;
  int swz = (b0 & 7) * (nb >> 3) + (b0 >> 3);
  const int bx = swz % gx, by = swz / gx;
  const int brow = by * 256, bcol = bx * 256;
  const int wr = w >> 2, wc = w & 3;   // 2M x 4N wave grid

  f32x4 acc[8][4];
#pragma unroll
  for (int i = 0; i < 8; ++i)
#pragma unroll
    for (int j = 0; j < 4; ++j) acc[i][j] = (f32x4){0.f, 0.f, 0.f, 0.f};

  const int srow = lane >> 2;          // 0..15
  const int scol = (lane & 3) * 8;     // 0,8,16,24
  const size_t ga0 = (size_t)(brow + (w * 2 + 0) * 16 + srow) * lda + scol;
  const size_t ga1 = (size_t)(brow + (w * 2 + 1) * 16 + srow) * lda + scol;
  const size_t gb0 = (size_t)(bcol + (w * 2 + 0) * 16 + srow) * ldb + scol;
  const size_t gb1 = (size_t)(bcol + (w * 2 + 1) * 16 + srow) * ldb + scol;

  const int fr = lane & 15, fk = (lane >> 4) * 8;
  const int NT = K >> 5;

  auto stage = [&](int ti, int b) {
    const int k0 = ti << 5;
    char* la = lds + b * 16384 + w * 2048;
    char* lb = lds + 49152 + b * 16384 + w * 2048;
    gload16(A + ga0 + k0, la);
    gload16(A + ga1 + k0, la + 1024);
    gload16(B + gb0 + k0, lb);
    gload16(B + gb1 + k0, lb + 1024);
  };

  stage(0, 0);
  stage(1, 1);

  int bR = 0;
  for (int it = 0; it < NT; ++it) {
    if (it + 1 < NT) { asm volatile("s_waitcnt vmcnt(4)" ::: "memory"); }
    else             { asm volatile("s_waitcnt vmcnt(0)" ::: "memory"); }
    __builtin_amdgcn_s_barrier();
    asm volatile("" ::: "memory");

    int bW = bR + 2; if (bW >= 3) bW -= 3;
    if (it + 2 < NT) stage(it + 2, bW);

    const u16* la = (const u16*)(lds + bR * 16384);
    const u16* lb = (const u16*)(lds + 49152 + bR * 16384);
    bf16x8 av[8], bv[4];
#pragma unroll
    for (int mi = 0; mi < 8; ++mi)
      av[mi] = *(const bf16x8*)&la[(wr * 128 + mi * 16 + fr) * 32 + fk];
#pragma unroll
    for (int ni = 0; ni < 4; ++ni)
      bv[ni] = *(const bf16x8*)&lb[(wc * 64 + ni * 16 + fr) * 32 + fk];

    __builtin_amdgcn_s_setprio(1);
#pragma unroll
    for (int mi = 0; mi < 8; ++mi)
#pragma unroll
      for (int ni = 0; ni < 4; ++ni)
        acc[mi][ni] = __builtin_amdgcn_mfma_f32_16x16x32_bf16(av[mi], bv[ni], acc[mi][ni], 0, 0, 0);
    __builtin_amdgcn_s_setprio(0);

    bR = (bR + 1 == 3) ? 0 : bR + 1;
  }

  const int fq = lane >> 4;
  __syncthreads();                     // retire all main-loop LDS reads

  // exp in place + per-row partial sums (over this wave's 64-col slice)
  float rsum[8][4];
#pragma unroll
  for (int mi = 0; mi < 8; ++mi) {
#pragma unroll
    for (int r = 0; r < 4; ++r) rsum[mi][r] = 0.f;
#pragma unroll
    for (int ni = 0; ni < 4; ++ni)
#pragma unroll
      for (int r = 0; r < 4; ++r) {
        float v = __expf(acc[mi][ni][r] * alpha);
        acc[mi][ni][r] = v;
        rsum[mi][r] += v;
      }
  }
#pragma unroll
  for (int mi = 0; mi < 8; ++mi)
#pragma unroll
    for (int r = 0; r < 4; ++r) {
      float s = rsum[mi][r];
      s += __shfl_xor(s, 1); s += __shfl_xor(s, 2);
      s += __shfl_xor(s, 4); s += __shfl_xor(s, 8);
      rsum[mi][r] = s;
    }
  float* wsum = (float*)(lds + 73728);   // [4 wc][256 rows], disjoint from tile
  if (fr == 0) {
#pragma unroll
    for (int mi = 0; mi < 8; ++mi)
#pragma unroll
      for (int r = 0; r < 4; ++r)
        wsum[wc * 256 + wr * 128 + mi * 16 + fq * 4 + r] = rsum[mi][r];
  }

  // C-write via two 256x128 LDS stripes (coalesced 256B rows)
  u16* tile = (u16*)lds;                 // [256][136] u16 = 68KB
#pragma unroll
  for (int s = 0; s < 2; ++s) {
    if ((wc >> 1) == s) {
#pragma unroll
      for (int mi = 0; mi < 8; ++mi)
#pragma unroll
        for (int ni = 0; ni < 4; ++ni) {
          int cc = (wc & 1) * 64 + ni * 16 + fr;
#pragma unroll
          for (int r = 0; r < 4; ++r) {
            int rr = wr * 128 + mi * 16 + fq * 4 + r;
            tile[rr * 136 + cc] = f2bf(acc[mi][ni][r]);
          }
        }
    }
    __syncthreads();                     // tile written (also fences wsum)
    {
      int row = tid >> 1, part = tid & 1;
      size_t base = (size_t)(brow + row) * N + bcol + s * 128 + part * 64;
      const u16* tr = &tile[row * 136 + part * 64];
#pragma unroll
      for (int j = 0; j < 8; ++j)
        *(bf16x8*)&C[base + j * 8] = *(const bf16x8*)&tr[j * 8];
    }
    __syncthreads();                     // stores done before tile reuse
  }

  if (tid < 256) {
    float s = wsum[tid] + wsum[256 + tid] + wsum[512 + tid] + wsum[768 + tid];
    dsum[(size_t)(brow + tid) * 16 + bx] = s;
  }
}

// ---------------- NT bf16 MFMA GEMM: C[M,N] = alpha*A[M,K]@B[N,K]^T + bias ----
// 128x128 tile, BK=32, 3 LDS buffers, stage-2-ahead, counted vmcnt,
// XCD-swizzled blockIdx (total grid %8==0 required).
// TRANST: additionally write C^T (bf16) via LDS-transposed coalesced stores.
// BCAST16: write each C value to 16 row-copies of out[N][16][768] via
//   LDS-staged 64-row stripes + fully-coalesced f32x4 NT stores.
// blockIdx.z = split-K slice: A/B advance by kofs elements, Cf by cofs.
template<bool RELU, bool BF16OUT, bool TRANST, bool BCAST16>
__global__ __launch_bounds__(256, 3) void gemm_nt(
    const u16* __restrict__ A, const u16* __restrict__ B,
    const float* __restrict__ bias, float alpha,
    float* __restrict__ Cf, u16* __restrict__ Cb,
    u16* __restrict__ Ct, int ldt,
    int M, int N, int K, int lda, int ldb,
    int kofs, long long cofs)
{
  __shared__ char lds[49152];            // 3 bufs x (A 8KB + B 8KB)
  const int t = threadIdx.x;
  const int w = t >> 6, lane = t & 63;

  // XCD-aware bijective swizzle over the flattened grid
  const int gx = gridDim.x, gy = gridDim.y;
  const int nb = gx * gy * gridDim.z;
  int b0 = (blockIdx.z * gy + blockIdx.y) * gx + blockIdx.x;
  int swz = (b0 & 7) * (nb >> 3) + (b0 >> 3);
  const int bx = swz % gx;
  int tmp = swz / gx;
  const int by = tmp % gy, kz = tmp / gy;

  const int brow = by * 128, bcol = bx * 128;
  const int wr = w >> 1, wc = w & 1;     // wave sub-tile 64x64

  A += (size_t)kz * kofs;
  B += (size_t)kz * kofs;
  Cf += kz * cofs;

  f32x4 acc[4][4];
#pragma unroll
  for (int i = 0; i < 4; ++i)
#pragma unroll
    for (int j = 0; j < 4; ++j) acc[i][j] = (f32x4){0.f, 0.f, 0.f, 0.f};

  const int srow = t >> 2;               // 0..63
  const int scol = (t & 3) * 8;
  const size_t aoff0 = (size_t)(brow + srow) * lda + scol;
  const size_t boff0 = (size_t)(bcol + srow) * ldb + scol;
  const size_t aoff1 = aoff0 + (size_t)64 * lda;
  const size_t boff1 = boff0 + (size_t)64 * ldb;

  const int fr = lane & 15, fk = (lane >> 4) * 8;
  const int NT = K >> 5;

  auto stage = [&](int ti, int b) {
    const int k0 = ti << 5;
    char* la = lds + b * 16384 + w * 1024;
    char* lb = lds + b * 16384 + 8192 + w * 1024;
    gload16(A + aoff0 + k0, la);
    gload16(A + aoff1 + k0, la + 4096);
    gload16(B + boff0 + k0, lb);
    gload16(B + boff1 + k0, lb + 4096);
  };

  stage(0, 0);
  stage(1, 1);

  int bR = 0;
  for (int it = 0; it < NT; ++it) {
    if (it + 1 < NT) { asm volatile("s_waitcnt vmcnt(4)" ::: "memory"); }
    else             { asm volatile("s_waitcnt vmcnt(0)" ::: "memory"); }
    __builtin_amdgcn_s_barrier();
    asm volatile("" ::: "memory");

    int bW = bR + 2; if (bW >= 3) bW -= 3;
    if (it + 2 < NT) stage(it + 2, bW);

    const u16* la = (const u16*)(lds + bR * 16384);
    const u16* lb = (const u16*)(lds + bR * 16384 + 8192);
    bf16x8 av[4], bv[4];
#pragma unroll
    for (int mi = 0; mi < 4; ++mi)
      av[mi] = *(const bf16x8*)&la[(wr * 64 + mi * 16 + fr) * 32 + fk];
#pragma unroll
    for (int ni = 0; ni < 4; ++ni)
      bv[ni] = *(const bf16x8*)&lb[(wc * 64 + ni * 16 + fr) * 32 + fk];

    __builtin_amdgcn_s_setprio(1);
#pragma unroll
    for (int mi = 0; mi < 4; ++mi)
#pragma unroll
      for (int ni = 0; ni < 4; ++ni)
        acc[mi][ni] = __builtin_amdgcn_mfma_f32_16x16x32_bf16(av[mi], bv[ni], acc[mi][ni], 0, 0, 0);
    __builtin_amdgcn_s_setprio(0);

    bR = (bR + 1 == 3) ? 0 : bR + 1;
  }

  const int fq = lane >> 4;

  if (BCAST16) {
    // apply alpha+bias in registers, then two 64-row stripes:
    // stage stripe in LDS [64][132] fp32 (33.8KB), then broadcast-write
    // out[n][l][d] with consecutive-tid -> consecutive-address f32x4 NT.
    float* tf = (float*)lds;             // [64][132]
#pragma unroll
    for (int s = 0; s < 2; ++s) {
      __syncthreads();                   // staging bufs / prev stripe free
      if (wr == s) {
#pragma unroll
        for (int mi = 0; mi < 4; ++mi)
#pragma unroll
          for (int ni = 0; ni < 4; ++ni) {
            int cl = wc * 64 + ni * 16 + fr;
            float bb = bias ? bias[bcol + cl] : 0.f;
#pragma unroll
            for (int r = 0; r < 4; ++r) {
              int rl = mi * 16 + fq * 4 + r;   // 0..63
              tf[rl * 132 + cl] = acc[mi][ni][r] * alpha + bb;
            }
          }
      }
      __syncthreads();
      // 64 rows x 16 copies x 128 floats = 32768 f32x4 / 256 thr = 128 each
      f32x4* O = (f32x4*)Cf;             // Cf = out base (fp32)
#pragma unroll 4
      for (int p = 0; p < 128; ++p) {
        int idx = p * 256 + t;
        int within = idx & 31;           // f32x4 within 512B segment
        int seg = idx >> 5;              // 0..1023
        int l = seg & 15, rl = seg >> 4;
        f32x4 v = *(const f32x4*)&tf[rl * 132 + within * 4];
        size_t o4 = ((size_t)(brow + s * 64 + rl) * 16 + l) * 192 + (bcol >> 2) + within;
        __builtin_nontemporal_store(v, &O[o4]);
      }
    }
    return;
  }

  u16* tileT = (u16*)lds;                // [128 cols][130] when TRANST
  if (TRANST) __syncthreads();           // all waves done reading lds bufs

#pragma unroll
  for (int mi = 0; mi < 4; ++mi) {
#pragma unroll
    for (int ni = 0; ni < 4; ++ni) {
      int cl = wc * 64 + ni * 16 + fr;
      int col = bcol + cl;
      float bb = bias ? bias[col] : 0.f;
#pragma unroll
      for (int r = 0; r < 4; ++r) {
        int rl = wr * 64 + mi * 16 + fq * 4 + r;
        int row = brow + rl;
        float v = acc[mi][ni][r] * alpha + bb;
        if (RELU) v = fmaxf(v, 0.f);
        if (BF16OUT) {
          u16 bf = f2bf(v);
          Cb[(size_t)row * N + col] = bf;
          if (TRANST) tileT[cl * 130 + rl] = bf;
        } else {
          Cf[(size_t)row * N + col] = v;
        }
      }
    }
  }

  if (TRANST) {
    __syncthreads();
    int c2 = t >> 1, off = (t & 1) * 64;
    size_t base = (size_t)(bcol + c2) * ldt + brow + off;
#pragma unroll
    for (int j = 0; j < 8; ++j)
      *(bf16x8*)&Ct[base + j * 8] = *(const bf16x8*)&tileT[c2 * 130 + off + j * 8];
  }
}

// -- LayerNorm rows (D=768): sum 2 split-K partials, scale by 1/denom, LN -----
__global__ __launch_bounds__(256) void ln2_kernel(
    const float* __restrict__ X, long long ps, const float* __restrict__ dsum,
    const float* __restrict__ g, const float* __restrict__ b,
    u16* __restrict__ Y)
{
  __shared__ float red[4];
  int row = blockIdx.x, t = threadIdx.x;
  const float* x = X + (size_t)row * 768;
  const f32x4* dv = (const f32x4*)(dsum + (size_t)row * 16);
  f32x4 d4 = dv[0] + dv[1] + dv[2] + dv[3];
  float inv_d = 1.f / (d4.x + d4.y + d4.z + d4.w);

  float v0 = (x[t]       + x[ps + t])       * inv_d;
  float v1 = (x[t + 256] + x[ps + t + 256]) * inv_d;
  float v2 = (x[t + 512] + x[ps + t + 512]) * inv_d;

  float s = v0 + v1 + v2;
#pragma unroll
  for (int off = 32; off > 0; off >>= 1) s += __shfl_xor(s, off);
  if ((t & 63) == 0) red[t >> 6] = s;
  __syncthreads();
  float mu = (red[0] + red[1] + red[2] + red[3]) * (1.f / 768.f);
  __syncthreads();

  float d0 = v0 - mu, d1 = v1 - mu, d2 = v2 - mu;
  float q = d0 * d0 + d1 * d1 + d2 * d2;
#pragma unroll
  for (int off = 32; off > 0; off >>= 1) q += __shfl_xor(q, off);
  if ((t & 63) == 0) red[t >> 6] = q;
  __syncthreads();
  float var = (red[0] + red[1] + red[2] + red[3]) * (1.f / 768.f);
  float inv = rsqrtf(var + 1e-5f);

  u16* y = Y + (size_t)row * 768;
  y[t]       = f2bf(d0 * inv * g[t]       + b[t]);
  y[t + 256] = f2bf(d1 * inv * g[t + 256] + b[t + 256]);
  y[t + 512] = f2bf(d2 * inv * g[t + 512] + b[t + 512]);
}

extern "C" void kernel_launch(void* const* d_in, const int* in_sizes, int n_in,
                              void* d_out, int out_size, void* d_ws, size_t ws_size,
                              hipStream_t stream)
{
  const float* vision = (const float*)d_in[0];
  const float* text   = (const float*)d_in[1];
  const float* fc_w   = (const float*)d_in[2];
  const float* fc_b   = (const float*)d_in[3];
  const float* ln_g   = (const float*)d_in[4];
  const float* ln_b   = (const float*)d_in[5];
  const float* w1     = (const float*)d_in[6];
  const float* b1     = (const float*)d_in[7];
  const float* w2     = (const float*)d_in[8];
  const float* b2     = (const float*)d_in[9];
  float* out = (float*)d_out;

  const int N = 4096, M = 4096, Din = 512, D = 768, Dhp = 256;

  char* p = (char*)d_ws;
  auto alloc = [&](size_t bytes) { char* r = p; p += (bytes + 255) & ~(size_t)255; return r; };
  u16*   mean_v = (u16*)alloc((size_t)N * D * 2);
  u16*   mean_t = (u16*)alloc((size_t)M * Din * 2);
  u16*   fcw_bf = (u16*)alloc((size_t)D * Din * 2);
  u16*   w1p    = (u16*)alloc((size_t)Dhp * D * 2);
  u16*   w2p    = (u16*)alloc((size_t)D * Dhp * 2);
  float* b1p    = (float*)alloc((size_t)Dhp * 4);
  float* dsum   = (float*)alloc((size_t)N * 16 * 4);
  u16*   t_bf   = (u16*)alloc((size_t)M * D * 2);
  u16*   tT_bf  = (u16*)alloc((size_t)D * M * 2);
  u16*   aff    = (u16*)alloc((size_t)N * M * 2);   // exp(scores), unnormalized
  u16*   ln_o   = (u16*)alloc((size_t)N * D * 2);
  u16*   h1     = (u16*)alloc((size_t)N * Dhp * 2);
  float* aggp   = (float*)alloc((size_t)2 * N * D * 4);  // 2 split-K partials

  // 1. fused prologue — MEASUREMENT ROUND: launched 3x (idempotent).
  //    dur_total ≈ base + 2*P  =>  P = (dur - 310us) / 2.
  {
    int total = 4096 * 192 + 4096 * 128 + 768 * 512 + 256 * 768 + 768 * 256 + 256;
    int nblk = (total + 255) / 256;
    prologue_kernel<<<nblk, 256, 0, stream>>>(
        vision, text, fc_w, w1, w2, b1, mean_v, mean_t, fcw_bf, w1p, w2p, b1p);
    prologue_kernel<<<nblk, 256, 0, stream>>>(
        vision, text, fc_w, w1, w2, b1, mean_v, mean_t, fcw_bf, w1p, w2p, b1p);
    prologue_kernel<<<nblk, 256, 0, stream>>>(
        vision, text, fc_w, w1, w2, b1, mean_v, mean_t, fcw_bf, w1p, w2p, b1p);
  }

  // 2. t = mean_t @ fc_w^T + fc_b  [M, D] bf16 + fused transpose tT [D, M]
  gemm_nt<false, true, true, false><<<dim3(D / 128, M / 128), 256, 0, stream>>>(
      mean_t, fcw_bf, fc_b, 1.f, nullptr, t_bf, tT_bf, M, M, D, Din, Din, Din, 0, 0);

  // 3. aff = exp(mean_v @ t^T / sqrt(D))  [N, M] bf16 + fused row-sum partials
  gemm256_exp_bf16<<<dim3(M / 256, N / 256), 512, 0, stream>>>(
      mean_v, t_bf, 1.f / sqrtf(768.f), aff, dsum, M, D, D, D);

  // 4. agg~ = aff @ t  [N, D] fp32, split-K=2 partials (B = tT, NT form)
  gemm_nt<false, false, false, false><<<dim3(D / 128, N / 128, 2), 256, 0, stream>>>(
      aff, tT_bf, nullptr, 1.f, aggp, nullptr, nullptr, 0, N, D, M / 2, M, M,
      M / 2, (long long)N * D);

  // 5. LayerNorm of (partial-sum / denom) -> bf16
  ln2_kernel<<<N, 256, 0, stream>>>(aggp, (long long)N * D, dsum, ln_g, ln_b, ln_o);

  // 6. h1 = relu(ln @ w1^T + b1)   [N, Dhp] bf16  (padded 192->256)
  gemm_nt<true, true, false, false><<<dim3(Dhp / 128, N / 128), 256, 0, stream>>>(
      ln_o, w1p, b1p, 1.f, nullptr, h1, nullptr, 0, N, Dhp, D, D, D, 0, 0);

  // 7. h2 = h1 @ w2^T + b2, broadcast-written to out[N][16][768]
  //    (LDS-staged stripes, fully-coalesced f32x4 NT stores)
  gemm_nt<false, false, false, true><<<dim3(D / 128, N / 128), 256, 0, stream>>>(
      h1, w2p, b2, 1.f, out, nullptr, nullptr, 0, N, D, Dhp, Dhp, Dhp, 0, 0);
}

// Round 13
// 310.869 us; speedup vs baseline: 1.9370x; 1.9370x over previous
//
#include <hip/hip_runtime.h>
#include <math.h>

typedef unsigned short u16;
typedef __attribute__((ext_vector_type(4))) float f32x4;
typedef __attribute__((ext_vector_type(8))) short bf16x8;

#define GLOBAL_AS __attribute__((address_space(1)))
#define LDS_AS __attribute__((address_space(3)))

__device__ __forceinline__ u16 f2bf(float f) {
  unsigned u = __builtin_bit_cast(unsigned, f);
  unsigned lsb = (u >> 16) & 1u;
  u += 0x7fffu + lsb;            // round-to-nearest-even
  return (u16)(u >> 16);
}

__device__ __forceinline__ float bf2f(u16 b) {
  return __builtin_bit_cast(float, ((unsigned)b) << 16);
}

__device__ __forceinline__ void gload16(const void* g, void* l) {
  __builtin_amdgcn_global_load_lds((const GLOBAL_AS void*)g, (LDS_AS void*)l, 16, 0, 0);
}

// ---- fused prologue: mean_v, mean_t, cast fc_w, pad-cast w1,w2, pad b1 ------
// MEASURED (R12): ~146us, 876MB @ 6.0 TB/s = 95% of achievable -> at roofline.
__global__ __launch_bounds__(256) void prologue_kernel(
    const float* __restrict__ vision, const float* __restrict__ text,
    const float* __restrict__ fc_w, const float* __restrict__ w1,
    const float* __restrict__ w2, const float* __restrict__ b1,
    u16* __restrict__ mean_v, u16* __restrict__ mean_t,
    u16* __restrict__ fcw_bf, u16* __restrict__ w1p, u16* __restrict__ w2p,
    float* __restrict__ b1p)
{
  const int n_mv = 4096 * 192;   // N * D/4
  const int n_mt = 4096 * 128;   // M * Din/4
  const int n_fcw = 768 * 512;
  const int n_w1 = 256 * 768;
  const int n_w2 = 768 * 256;
  int id = blockIdx.x * 256 + threadIdx.x;

  if (id < n_mv) {               // mean over Lv=16 of vision[N][16][768]
    int n = id / 192, c = id % 192;
    const f32x4* x = (const f32x4*)vision + (size_t)n * 16 * 192 + c;
    f32x4 s = {0.f, 0.f, 0.f, 0.f};
#pragma unroll
    for (int l = 0; l < 16; ++l) s += __builtin_nontemporal_load(&x[(size_t)l * 192]);
    s *= (1.f / 16.f);
    ushort4 o; o.x = f2bf(s.x); o.y = f2bf(s.y); o.z = f2bf(s.z); o.w = f2bf(s.w);
    ((ushort4*)mean_v)[id] = o;
    return;
  }
  id -= n_mv;
  if (id < n_mt) {               // mean over Lt=77 of text[M][77][512]
    int n = id / 128, c = id % 128;
    const f32x4* x = (const f32x4*)text + (size_t)n * 77 * 128 + c;
    f32x4 s = {0.f, 0.f, 0.f, 0.f};
#pragma unroll 11
    for (int l = 0; l < 77; ++l) s += __builtin_nontemporal_load(&x[(size_t)l * 128]);
    s *= (1.f / 77.f);
    ushort4 o; o.x = f2bf(s.x); o.y = f2bf(s.y); o.z = f2bf(s.z); o.w = f2bf(s.w);
    ((ushort4*)mean_t)[id] = o;
    return;
  }
  id -= n_mt;
  if (id < n_fcw) { fcw_bf[id] = f2bf(fc_w[id]); return; }
  id -= n_fcw;
  if (id < n_w1) {
    int r = id / 768;
    w1p[id] = (r < 192) ? f2bf(w1[id]) : (u16)0;
    return;
  }
  id -= n_w1;
  if (id < n_w2) {
    int r = id / 256, c = id % 256;
    w2p[id] = (c < 192) ? f2bf(w2[(size_t)r * 192 + c]) : (u16)0;
    return;
  }
  id -= n_w2;
  if (id < 256) b1p[id] = (id < 192) ? b1[id] : 0.f;
}

// ------- 256x256 deep-pipelined NT bf16 GEMM, C bf16 = exp(alpha * A@B^T) ---
// BK=32, 3 LDS buffers, stage-2-ahead, counted vmcnt, 1 raw barrier per iter.
// XCD-swizzled blockIdx. C written via LDS-staged 256x128 stripes. Row
// exp-sums -> dsum[row][gridx] fp32 partials (deterministic, no atomics).
__global__ __launch_bounds__(512, 2) void gemm256_exp_bf16(
    const u16* __restrict__ A, const u16* __restrict__ B, float alpha,
    u16* __restrict__ C, float* __restrict__ dsum, int N, int K, int lda, int ldb)
{
  __shared__ char lds[98304];          // A bufs 0..48K, B bufs 48K..96K
  const int tid = threadIdx.x;
  const int w = tid >> 6, lane = tid & 63;

  // XCD-aware bijective swizzle
  const int gx = gridDim.x;
  const int nb = gx * gridDim.y;
  int b0 = blockIdx.y * gx + blockIdx.x;
  int swz = (b0 & 7) * (nb >> 3) + (b0 >> 3);
  const int bx = swz % gx, by = swz / gx;
  const int brow = by * 256, bcol = bx * 256;
  const int wr = w >> 2, wc = w & 3;   // 2M x 4N wave grid

  f32x4 acc[8][4];
#pragma unroll
  for (int i = 0; i < 8; ++i)
#pragma unroll
    for (int j = 0; j < 4; ++j) acc[i][j] = (f32x4){0.f, 0.f, 0.f, 0.f};

  const int srow = lane >> 2;          // 0..15
  const int scol = (lane & 3) * 8;     // 0,8,16,24
  const size_t ga0 = (size_t)(brow + (w * 2 + 0) * 16 + srow) * lda + scol;
  const size_t ga1 = (size_t)(brow + (w * 2 + 1) * 16 + srow) * lda + scol;
  const size_t gb0 = (size_t)(bcol + (w * 2 + 0) * 16 + srow) * ldb + scol;
  const size_t gb1 = (size_t)(bcol + (w * 2 + 1) * 16 + srow) * ldb + scol;

  const int fr = lane & 15, fk = (lane >> 4) * 8;
  const int NT = K >> 5;

  auto stage = [&](int ti, int b) {
    const int k0 = ti << 5;
    char* la = lds + b * 16384 + w * 2048;
    char* lb = lds + 49152 + b * 16384 + w * 2048;
    gload16(A + ga0 + k0, la);
    gload16(A + ga1 + k0, la + 1024);
    gload16(B + gb0 + k0, lb);
    gload16(B + gb1 + k0, lb + 1024);
  };

  stage(0, 0);
  stage(1, 1);

  int bR = 0;
  for (int it = 0; it < NT; ++it) {
    if (it + 1 < NT) { asm volatile("s_waitcnt vmcnt(4)" ::: "memory"); }
    else             { asm volatile("s_waitcnt vmcnt(0)" ::: "memory"); }
    __builtin_amdgcn_s_barrier();
    asm volatile("" ::: "memory");

    int bW = bR + 2; if (bW >= 3) bW -= 3;
    if (it + 2 < NT) stage(it + 2, bW);

    const u16* la = (const u16*)(lds + bR * 16384);
    const u16* lb = (const u16*)(lds + 49152 + bR * 16384);
    bf16x8 av[8], bv[4];
#pragma unroll
    for (int mi = 0; mi < 8; ++mi)
      av[mi] = *(const bf16x8*)&la[(wr * 128 + mi * 16 + fr) * 32 + fk];
#pragma unroll
    for (int ni = 0; ni < 4; ++ni)
      bv[ni] = *(const bf16x8*)&lb[(wc * 64 + ni * 16 + fr) * 32 + fk];

    __builtin_amdgcn_s_setprio(1);
#pragma unroll
    for (int mi = 0; mi < 8; ++mi)
#pragma unroll
      for (int ni = 0; ni < 4; ++ni)
        acc[mi][ni] = __builtin_amdgcn_mfma_f32_16x16x32_bf16(av[mi], bv[ni], acc[mi][ni], 0, 0, 0);
    __builtin_amdgcn_s_setprio(0);

    bR = (bR + 1 == 3) ? 0 : bR + 1;
  }

  const int fq = lane >> 4;
  __syncthreads();                     // retire all main-loop LDS reads

  // exp in place + per-row partial sums (over this wave's 64-col slice)
  float rsum[8][4];
#pragma unroll
  for (int mi = 0; mi < 8; ++mi) {
#pragma unroll
    for (int r = 0; r < 4; ++r) rsum[mi][r] = 0.f;
#pragma unroll
    for (int ni = 0; ni < 4; ++ni)
#pragma unroll
      for (int r = 0; r < 4; ++r) {
        float v = __expf(acc[mi][ni][r] * alpha);
        acc[mi][ni][r] = v;
        rsum[mi][r] += v;
      }
  }
#pragma unroll
  for (int mi = 0; mi < 8; ++mi)
#pragma unroll
    for (int r = 0; r < 4; ++r) {
      float s = rsum[mi][r];
      s += __shfl_xor(s, 1); s += __shfl_xor(s, 2);
      s += __shfl_xor(s, 4); s += __shfl_xor(s, 8);
      rsum[mi][r] = s;
    }
  float* wsum = (float*)(lds + 73728);   // [4 wc][256 rows], disjoint from tile
  if (fr == 0) {
#pragma unroll
    for (int mi = 0; mi < 8; ++mi)
#pragma unroll
      for (int r = 0; r < 4; ++r)
        wsum[wc * 256 + wr * 128 + mi * 16 + fq * 4 + r] = rsum[mi][r];
  }

  // C-write via two 256x128 LDS stripes (coalesced 256B rows)
  u16* tile = (u16*)lds;                 // [256][136] u16 = 68KB
#pragma unroll
  for (int s = 0; s < 2; ++s) {
    if ((wc >> 1) == s) {
#pragma unroll
      for (int mi = 0; mi < 8; ++mi)
#pragma unroll
        for (int ni = 0; ni < 4; ++ni) {
          int cc = (wc & 1) * 64 + ni * 16 + fr;
#pragma unroll
          for (int r = 0; r < 4; ++r) {
            int rr = wr * 128 + mi * 16 + fq * 4 + r;
            tile[rr * 136 + cc] = f2bf(acc[mi][ni][r]);
          }
        }
    }
    __syncthreads();                     // tile written (also fences wsum)
    {
      int row = tid >> 1, part = tid & 1;
      size_t base = (size_t)(brow + row) * N + bcol + s * 128 + part * 64;
      const u16* tr = &tile[row * 136 + part * 64];
#pragma unroll
      for (int j = 0; j < 8; ++j)
        *(bf16x8*)&C[base + j * 8] = *(const bf16x8*)&tr[j * 8];
    }
    __syncthreads();                     // stores done before tile reuse
  }

  if (tid < 256) {
    float s = wsum[tid] + wsum[256 + tid] + wsum[512 + tid] + wsum[768 + tid];
    dsum[(size_t)(brow + tid) * 16 + bx] = s;
  }
}

// ---------------- NT bf16 MFMA GEMM: C[M,N] = alpha*A[M,K]@B[N,K]^T + bias ----
// 128x128 tile, BK=32, 3 LDS buffers, stage-2-ahead, counted vmcnt,
// XCD-swizzled blockIdx (total grid %8==0 required).
// TRANST: additionally write C^T (bf16) via LDS-transposed coalesced stores.
// BCAST16: write each C value to 16 row-copies of out[N][16][768] via
//   LDS-staged 64-row stripes + fully-coalesced f32x4 NT stores.
// blockIdx.z = split-K slice: A/B advance by kofs elements, Cf by cofs.
template<bool RELU, bool BF16OUT, bool TRANST, bool BCAST16>
__global__ __launch_bounds__(256, 3) void gemm_nt(
    const u16* __restrict__ A, const u16* __restrict__ B,
    const float* __restrict__ bias, float alpha,
    float* __restrict__ Cf, u16* __restrict__ Cb,
    u16* __restrict__ Ct, int ldt,
    int M, int N, int K, int lda, int ldb,
    int kofs, long long cofs)
{
  __shared__ char lds[49152];            // 3 bufs x (A 8KB + B 8KB)
  const int t = threadIdx.x;
  const int w = t >> 6, lane = t & 63;

  // XCD-aware bijective swizzle over the flattened grid
  const int gx = gridDim.x, gy = gridDim.y;
  const int nb = gx * gy * gridDim.z;
  int b0 = (blockIdx.z * gy + blockIdx.y) * gx + blockIdx.x;
  int swz = (b0 & 7) * (nb >> 3) + (b0 >> 3);
  const int bx = swz % gx;
  int tmp = swz / gx;
  const int by = tmp % gy, kz = tmp / gy;

  const int brow = by * 128, bcol = bx * 128;
  const int wr = w >> 1, wc = w & 1;     // wave sub-tile 64x64

  A += (size_t)kz * kofs;
  B += (size_t)kz * kofs;
  Cf += kz * cofs;

  f32x4 acc[4][4];
#pragma unroll
  for (int i = 0; i < 4; ++i)
#pragma unroll
    for (int j = 0; j < 4; ++j) acc[i][j] = (f32x4){0.f, 0.f, 0.f, 0.f};

  const int srow = t >> 2;               // 0..63
  const int scol = (t & 3) * 8;
  const size_t aoff0 = (size_t)(brow + srow) * lda + scol;
  const size_t boff0 = (size_t)(bcol + srow) * ldb + scol;
  const size_t aoff1 = aoff0 + (size_t)64 * lda;
  const size_t boff1 = boff0 + (size_t)64 * ldb;

  const int fr = lane & 15, fk = (lane >> 4) * 8;
  const int NT = K >> 5;

  auto stage = [&](int ti, int b) {
    const int k0 = ti << 5;
    char* la = lds + b * 16384 + w * 1024;
    char* lb = lds + b * 16384 + 8192 + w * 1024;
    gload16(A + aoff0 + k0, la);
    gload16(A + aoff1 + k0, la + 4096);
    gload16(B + boff0 + k0, lb);
    gload16(B + boff1 + k0, lb + 4096);
  };

  stage(0, 0);
  stage(1, 1);

  int bR = 0;
  for (int it = 0; it < NT; ++it) {
    if (it + 1 < NT) { asm volatile("s_waitcnt vmcnt(4)" ::: "memory"); }
    else             { asm volatile("s_waitcnt vmcnt(0)" ::: "memory"); }
    __builtin_amdgcn_s_barrier();
    asm volatile("" ::: "memory");

    int bW = bR + 2; if (bW >= 3) bW -= 3;
    if (it + 2 < NT) stage(it + 2, bW);

    const u16* la = (const u16*)(lds + bR * 16384);
    const u16* lb = (const u16*)(lds + bR * 16384 + 8192);
    bf16x8 av[4], bv[4];
#pragma unroll
    for (int mi = 0; mi < 4; ++mi)
      av[mi] = *(const bf16x8*)&la[(wr * 64 + mi * 16 + fr) * 32 + fk];
#pragma unroll
    for (int ni = 0; ni < 4; ++ni)
      bv[ni] = *(const bf16x8*)&lb[(wc * 64 + ni * 16 + fr) * 32 + fk];

    __builtin_amdgcn_s_setprio(1);
#pragma unroll
    for (int mi = 0; mi < 4; ++mi)
#pragma unroll
      for (int ni = 0; ni < 4; ++ni)
        acc[mi][ni] = __builtin_amdgcn_mfma_f32_16x16x32_bf16(av[mi], bv[ni], acc[mi][ni], 0, 0, 0);
    __builtin_amdgcn_s_setprio(0);

    bR = (bR + 1 == 3) ? 0 : bR + 1;
  }

  const int fq = lane >> 4;

  if (BCAST16) {
    // apply alpha+bias in registers, then two 64-row stripes:
    // stage stripe in LDS [64][132] fp32 (33.8KB), then broadcast-write
    // out[n][l][d] with consecutive-tid -> consecutive-address f32x4 NT.
    float* tf = (float*)lds;             // [64][132]
#pragma unroll
    for (int s = 0; s < 2; ++s) {
      __syncthreads();                   // staging bufs / prev stripe free
      if (wr == s) {
#pragma unroll
        for (int mi = 0; mi < 4; ++mi)
#pragma unroll
          for (int ni = 0; ni < 4; ++ni) {
            int cl = wc * 64 + ni * 16 + fr;
            float bb = bias ? bias[bcol + cl] : 0.f;
#pragma unroll
            for (int r = 0; r < 4; ++r) {
              int rl = mi * 16 + fq * 4 + r;   // 0..63
              tf[rl * 132 + cl] = acc[mi][ni][r] * alpha + bb;
            }
          }
      }
      __syncthreads();
      // 64 rows x 16 copies x 128 floats = 32768 f32x4 / 256 thr = 128 each
      f32x4* O = (f32x4*)Cf;             // Cf = out base (fp32)
#pragma unroll 4
      for (int p = 0; p < 128; ++p) {
        int idx = p * 256 + t;
        int within = idx & 31;           // f32x4 within 512B segment
        int seg = idx >> 5;              // 0..1023
        int l = seg & 15, rl = seg >> 4;
        f32x4 v = *(const f32x4*)&tf[rl * 132 + within * 4];
        size_t o4 = ((size_t)(brow + s * 64 + rl) * 16 + l) * 192 + (bcol >> 2) + within;
        __builtin_nontemporal_store(v, &O[o4]);
      }
    }
    return;
  }

  u16* tileT = (u16*)lds;                // [128 cols][130] when TRANST
  if (TRANST) __syncthreads();           // all waves done reading lds bufs

#pragma unroll
  for (int mi = 0; mi < 4; ++mi) {
#pragma unroll
    for (int ni = 0; ni < 4; ++ni) {
      int cl = wc * 64 + ni * 16 + fr;
      int col = bcol + cl;
      float bb = bias ? bias[col] : 0.f;
#pragma unroll
      for (int r = 0; r < 4; ++r) {
        int rl = wr * 64 + mi * 16 + fq * 4 + r;
        int row = brow + rl;
        float v = acc[mi][ni][r] * alpha + bb;
        if (RELU) v = fmaxf(v, 0.f);
        if (BF16OUT) {
          u16 bf = f2bf(v);
          Cb[(size_t)row * N + col] = bf;
          if (TRANST) tileT[cl * 130 + rl] = bf;
        } else {
          Cf[(size_t)row * N + col] = v;
        }
      }
    }
  }

  if (TRANST) {
    __syncthreads();
    int c2 = t >> 1, off = (t & 1) * 64;
    size_t base = (size_t)(bcol + c2) * ldt + brow + off;
#pragma unroll
    for (int j = 0; j < 8; ++j)
      *(bf16x8*)&Ct[base + j * 8] = *(const bf16x8*)&tileT[c2 * 130 + off + j * 8];
  }
}

// -- LayerNorm rows (D=768): sum 4 split-K partials, scale by 1/denom, LN -----
__global__ __launch_bounds__(256) void ln4_kernel(
    const float* __restrict__ X, long long ps, const float* __restrict__ dsum,
    const float* __restrict__ g, const float* __restrict__ b,
    u16* __restrict__ Y)
{
  __shared__ float red[4];
  int row = blockIdx.x, t = threadIdx.x;
  const float* x = X + (size_t)row * 768;
  const f32x4* dv = (const f32x4*)(dsum + (size_t)row * 16);
  f32x4 d4 = dv[0] + dv[1] + dv[2] + dv[3];
  float inv_d = 1.f / (d4.x + d4.y + d4.z + d4.w);

  float v0 = (x[t]       + x[ps + t]       + x[2 * ps + t]       + x[3 * ps + t]) * inv_d;
  float v1 = (x[t + 256] + x[ps + t + 256] + x[2 * ps + t + 256] + x[3 * ps + t + 256]) * inv_d;
  float v2 = (x[t + 512] + x[ps + t + 512] + x[2 * ps + t + 512] + x[3 * ps + t + 512]) * inv_d;

  float s = v0 + v1 + v2;
#pragma unroll
  for (int off = 32; off > 0; off >>= 1) s += __shfl_xor(s, off);
  if ((t & 63) == 0) red[t >> 6] = s;
  __syncthreads();
  float mu = (red[0] + red[1] + red[2] + red[3]) * (1.f / 768.f);
  __syncthreads();

  float d0 = v0 - mu, d1 = v1 - mu, d2 = v2 - mu;
  float q = d0 * d0 + d1 * d1 + d2 * d2;
#pragma unroll
  for (int off = 32; off > 0; off >>= 1) q += __shfl_xor(q, off);
  if ((t & 63) == 0) red[t >> 6] = q;
  __syncthreads();
  float var = (red[0] + red[1] + red[2] + red[3]) * (1.f / 768.f);
  float inv = rsqrtf(var + 1e-5f);

  u16* y = Y + (size_t)row * 768;
  y[t]       = f2bf(d0 * inv * g[t]       + b[t]);
  y[t + 256] = f2bf(d1 * inv * g[t + 256] + b[t + 256]);
  y[t + 512] = f2bf(d2 * inv * g[t + 512] + b[t + 512]);
}

extern "C" void kernel_launch(void* const* d_in, const int* in_sizes, int n_in,
                              void* d_out, int out_size, void* d_ws, size_t ws_size,
                              hipStream_t stream)
{
  const float* vision = (const float*)d_in[0];
  const float* text   = (const float*)d_in[1];
  const float* fc_w   = (const float*)d_in[2];
  const float* fc_b   = (const float*)d_in[3];
  const float* ln_g   = (const float*)d_in[4];
  const float* ln_b   = (const float*)d_in[5];
  const float* w1     = (const float*)d_in[6];
  const float* b1     = (const float*)d_in[7];
  const float* w2     = (const float*)d_in[8];
  const float* b2     = (const float*)d_in[9];
  float* out = (float*)d_out;

  const int N = 4096, M = 4096, Din = 512, D = 768, Dhp = 256;

  char* p = (char*)d_ws;
  auto alloc = [&](size_t bytes) { char* r = p; p += (bytes + 255) & ~(size_t)255; return r; };
  u16*   mean_v = (u16*)alloc((size_t)N * D * 2);
  u16*   mean_t = (u16*)alloc((size_t)M * Din * 2);
  u16*   fcw_bf = (u16*)alloc((size_t)D * Din * 2);
  u16*   w1p    = (u16*)alloc((size_t)Dhp * D * 2);
  u16*   w2p    = (u16*)alloc((size_t)D * Dhp * 2);
  float* b1p    = (float*)alloc((size_t)Dhp * 4);
  float* dsum   = (float*)alloc((size_t)N * 16 * 4);
  u16*   t_bf   = (u16*)alloc((size_t)M * D * 2);
  u16*   tT_bf  = (u16*)alloc((size_t)D * M * 2);
  u16*   aff    = (u16*)alloc((size_t)N * M * 2);   // exp(scores), unnormalized
  u16*   ln_o   = (u16*)alloc((size_t)N * D * 2);
  u16*   h1     = (u16*)alloc((size_t)N * Dhp * 2);
  float* aggp   = (float*)alloc((size_t)4 * N * D * 4);  // 4 split-K partials

  // 1. fused prologue: means + weight casts/pads (measured: at roofline)
  {
    int total = 4096 * 192 + 4096 * 128 + 768 * 512 + 256 * 768 + 768 * 256 + 256;
    prologue_kernel<<<(total + 255) / 256, 256, 0, stream>>>(
        vision, text, fc_w, w1, w2, b1, mean_v, mean_t, fcw_bf, w1p, w2p, b1p);
  }

  // 2. t = mean_t @ fc_w^T + fc_b  [M, D] bf16 + fused transpose tT [D, M]
  gemm_nt<false, true, true, false><<<dim3(D / 128, M / 128), 256, 0, stream>>>(
      mean_t, fcw_bf, fc_b, 1.f, nullptr, t_bf, tT_bf, M, M, D, Din, Din, Din, 0, 0);

  // 3. aff = exp(mean_v @ t^T / sqrt(D))  [N, M] bf16 + fused row-sum partials
  gemm256_exp_bf16<<<dim3(M / 256, N / 256), 512, 0, stream>>>(
      mean_v, t_bf, 1.f / sqrtf(768.f), aff, dsum, M, D, D, D);

  // 4. agg~ = aff @ t  [N, D] fp32, split-K=4 partials -> 768 blocks = 3/CU
  gemm_nt<false, false, false, false><<<dim3(D / 128, N / 128, 4), 256, 0, stream>>>(
      aff, tT_bf, nullptr, 1.f, aggp, nullptr, nullptr, 0, N, D, M / 4, M, M,
      M / 4, (long long)N * D);

  // 5. LayerNorm of (4-partial-sum / denom) -> bf16
  ln4_kernel<<<N, 256, 0, stream>>>(aggp, (long long)N * D, dsum, ln_g, ln_b, ln_o);

  // 6. h1 = relu(ln @ w1^T + b1)   [N, Dhp] bf16  (padded 192->256)
  gemm_nt<true, true, false, false><<<dim3(Dhp / 128, N / 128), 256, 0, stream>>>(
      ln_o, w1p, b1p, 1.f, nullptr, h1, nullptr, 0, N, Dhp, D, D, D, 0, 0);

  // 7. h2 = h1 @ w2^T + b2, broadcast-written to out[N][16][768]
  //    (LDS-staged stripes, fully-coalesced f32x4 NT stores)
  gemm_nt<false, false, false, true><<<dim3(D / 128, N / 128), 256, 0, stream>>>(
      h1, w2p, b2, 1.f, out, nullptr, nullptr, 0, N, D, Dhp, Dhp, Dhp, 0, 0);
}